// Round 1
// baseline (20.169 us; speedup 1.0000x reference)
//
#include <hip/hip_runtime.h>

#define MAX_NODE 511
#define SLOTS (MAX_NODE + 1)   // 512
#define CDIM 1024              // channels (f32)

// One block per output row (b, slot). 256 threads x float4 = 1024 floats = 4 KiB row.
__global__ __launch_bounds__(256)
void graph_embed_kernel(const float* __restrict__ patch,   // [total_nodes, CDIM]
                        const float* __restrict__ cent,    // [total_nodes, 2]
                        const float* __restrict__ img,     // [B, CDIM]
                        const int*   __restrict__ nn,      // [B]
                        float* __restrict__ out, int B) {
    const int bid  = blockIdx.x;
    const int b    = bid >> 9;        // / SLOTS
    const int slot = bid & (SLOTS - 1);

    __shared__ int s_off, s_nn;
    if (threadIdx.x == 0) {
        int off = 0;
        for (int i = 0; i < b; ++i) off += nn[i];
        s_off = off;
        s_nn  = nn[b];
    }
    __syncthreads();

    const int n     = s_nn;
    const int n_eff = (n < MAX_NODE) ? n : MAX_NODE;
    const int off   = s_off;

    float* features = out;
    float* mask     = out + (size_t)B * SLOTS * CDIM;
    float* pos_x    = mask  + (size_t)B * SLOTS;
    float* pos_y    = pos_x + (size_t)B * SLOTS;

    const int t = threadIdx.x;
    float4 v;
    if (slot == 0) {
        v = reinterpret_cast<const float4*>(img + (size_t)b * CDIM)[t];
    } else {
        const int j = slot - 1;
        if (j < n_eff) {
            v = reinterpret_cast<const float4*>(patch + (size_t)(off + j) * CDIM)[t];
        } else {
            v = make_float4(0.f, 0.f, 0.f, 0.f);
        }
    }
    reinterpret_cast<float4*>(features + ((size_t)b * SLOTS + slot) * CDIM)[t] = v;

    if (t == 0) {
        const float m = (slot >= n + 1 && n <= MAX_NODE) ? 1.0f : 0.0f;
        float px = 0.f, py = 0.f;
        if (slot >= 1) {
            const int j = slot - 1;
            if (j < n_eff) {
                px = cent[(size_t)(off + j) * 2 + 0];
                py = cent[(size_t)(off + j) * 2 + 1];
            }
        }
        const size_t mi = (size_t)b * SLOTS + slot;
        mask[mi]  = m;
        pos_x[mi] = px;
        pos_y[mi] = py;
    }
}

extern "C" void kernel_launch(void* const* d_in, const int* in_sizes, int n_in,
                              void* d_out, int out_size, void* d_ws, size_t ws_size,
                              hipStream_t stream) {
    const float* patch = (const float*)d_in[0];   // [total_nodes, 1024]
    const float* cent  = (const float*)d_in[1];   // [total_nodes, 2]
    const float* img   = (const float*)d_in[2];   // [B, 1024]
    const int*   nn    = (const int*)d_in[3];     // [B]
    float* out = (float*)d_out;

    const int B = in_sizes[3];
    const int nblocks = B * SLOTS;
    graph_embed_kernel<<<nblocks, 256, 0, stream>>>(patch, cent, img, nn, out, B);
}